// Round 1
// baseline (528.870 us; speedup 1.0000x reference)
//
#include <hip/hip_runtime.h>
#include <hip/hip_bf16.h>

// Problem constants
constexpr int T_ = 16;
constexpr int D_ = 192;
constexpr int H_ = 128;
constexpr int P_ = 128;
constexpr int HEADS_ = 4;
constexpr int HD_ = 32;
constexpr int EC_ = 32;
constexpr int S_ = T_ * D_;       // 3072
constexpr int FF_ = 512;
constexpr float SCALE_ = 0.17677669529663687f;  // 1/sqrt(32)

// ---------------------------------------------------------------------------
// Fill kernel: logits <- -1e9 (masked entries stay, active entries overwritten)
// ---------------------------------------------------------------------------
__global__ void fill_kernel(float* __restrict__ p, float v, int n) {
  int i = blockIdx.x * blockDim.x + threadIdx.x;
  int stride = gridDim.x * blockDim.x;
  for (; i < n; i += stride) p[i] = v;
}

// ---------------------------------------------------------------------------
// Node embedding: z[s][p] = relu(sum_h x[t][h][d]*W_node[h][p] + b_node[p])
//                           + time_enc[p]*t      (s = t*D + d)
// ---------------------------------------------------------------------------
__global__ __launch_bounds__(128) void node_embed_kernel(
    const float* __restrict__ x, const float* __restrict__ W_node,
    const float* __restrict__ b_node, const float* __restrict__ time_enc,
    float* __restrict__ z) {
  int s0 = blockIdx.x * 8;
  int j = threadIdx.x;  // output column 0..127
  __shared__ float As[8 * H_];
  for (int idx = j; idx < 8 * H_; idx += 128) {
    int r = idx >> 7;
    int h = idx & 127;
    int s = s0 + r;
    int t = s / D_;
    int d = s - t * D_;
    As[idx] = x[(t * H_ + h) * D_ + d];
  }
  __syncthreads();
  float acc[8];
  float bj = b_node[j];
#pragma unroll
  for (int r = 0; r < 8; ++r) acc[r] = bj;
  for (int h = 0; h < H_; h += 4) {
    float4 w;
    w.x = W_node[(h + 0) * P_ + j];
    w.y = W_node[(h + 1) * P_ + j];
    w.z = W_node[(h + 2) * P_ + j];
    w.w = W_node[(h + 3) * P_ + j];
#pragma unroll
    for (int r = 0; r < 8; ++r) {
      const float4 a = *reinterpret_cast<const float4*>(&As[r * H_ + h]);
      acc[r] = fmaf(a.x, w.x, acc[r]);
      acc[r] = fmaf(a.y, w.y, acc[r]);
      acc[r] = fmaf(a.z, w.z, acc[r]);
      acc[r] = fmaf(a.w, w.w, acc[r]);
    }
  }
  float te = time_enc[j];
#pragma unroll
  for (int r = 0; r < 8; ++r) {
    int s = s0 + r;
    int t = s / D_;
    z[s * P_ + j] = fmaxf(acc[r], 0.f) + te * (float)t;
  }
}

// ---------------------------------------------------------------------------
// LayerNorm: one wave (64 lanes) per row of 128
// ---------------------------------------------------------------------------
__global__ __launch_bounds__(256) void ln_kernel(
    const float* __restrict__ z, const float* __restrict__ g,
    const float* __restrict__ b, float* __restrict__ y) {
  int row = blockIdx.x * 4 + (threadIdx.x >> 6);
  int lane = threadIdx.x & 63;
  const float* zr = z + row * P_;
  float v0 = zr[lane], v1 = zr[lane + 64];
  float s = v0 + v1;
#pragma unroll
  for (int m = 1; m < 64; m <<= 1) s += __shfl_xor(s, m);
  float mean = s * (1.f / P_);
  float d0 = v0 - mean, d1 = v1 - mean;
  float q = d0 * d0 + d1 * d1;
#pragma unroll
  for (int m = 1; m < 64; m <<= 1) q += __shfl_xor(q, m);
  float inv = 1.f / sqrtf(q * (1.f / P_) + 1e-5f);
  float* yr = y + row * P_;
  yr[lane] = d0 * inv * g[lane] + b[lane];
  yr[lane + 64] = d1 * inv * g[lane + 64] + b[lane + 64];
}

// ---------------------------------------------------------------------------
// Generic fp32 GEMM: C[M,N] = act(A[M,K] @ B[K,N] (+bias)) (+= if ACCUM)
// BM=8 rows per block, 2 cols per thread, block = N/2 threads.
// ---------------------------------------------------------------------------
template <int K, int N, bool RELU, bool ACCUM, bool BIAS>
__global__ __launch_bounds__(N / 2) void gemm_k(
    const float* __restrict__ A, const float* __restrict__ B,
    const float* __restrict__ bias, float* __restrict__ C) {
  constexpr int BM = 8;
  constexpr int NT = N / 2;
  int m0 = blockIdx.x * BM;
  int j = threadIdx.x;
  int c0 = 2 * j;
  __shared__ float As[BM * K];
  for (int idx = j; idx < BM * K; idx += NT) As[idx] = A[m0 * K + idx];
  __syncthreads();
  float acc0[BM], acc1[BM];
  float b0 = BIAS ? bias[c0] : 0.f;
  float b1 = BIAS ? bias[c0 + 1] : 0.f;
#pragma unroll
  for (int r = 0; r < BM; ++r) {
    acc0[r] = b0;
    acc1[r] = b1;
  }
  for (int k = 0; k < K; k += 4) {
    float2 bv0 = *reinterpret_cast<const float2*>(B + (k + 0) * N + c0);
    float2 bv1 = *reinterpret_cast<const float2*>(B + (k + 1) * N + c0);
    float2 bv2 = *reinterpret_cast<const float2*>(B + (k + 2) * N + c0);
    float2 bv3 = *reinterpret_cast<const float2*>(B + (k + 3) * N + c0);
#pragma unroll
    for (int r = 0; r < BM; ++r) {
      const float4 a = *reinterpret_cast<const float4*>(&As[r * K + k]);
      acc0[r] = fmaf(a.x, bv0.x, acc0[r]);
      acc1[r] = fmaf(a.x, bv0.y, acc1[r]);
      acc0[r] = fmaf(a.y, bv1.x, acc0[r]);
      acc1[r] = fmaf(a.y, bv1.y, acc1[r]);
      acc0[r] = fmaf(a.z, bv2.x, acc0[r]);
      acc1[r] = fmaf(a.z, bv2.y, acc1[r]);
      acc0[r] = fmaf(a.w, bv3.x, acc0[r]);
      acc1[r] = fmaf(a.w, bv3.y, acc1[r]);
    }
  }
#pragma unroll
  for (int r = 0; r < BM; ++r) {
    float v0 = acc0[r], v1 = acc1[r];
    if (RELU) {
      v0 = fmaxf(v0, 0.f);
      v1 = fmaxf(v1, 0.f);
    }
    float* cp = C + (m0 + r) * N + c0;
    if (ACCUM) {
      float2 old = *reinterpret_cast<float2*>(cp);
      old.x += v0;
      old.y += v1;
      *reinterpret_cast<float2*>(cp) = old;
    } else {
      float2 nv;
      nv.x = v0;
      nv.y = v1;
      *reinterpret_cast<float2*>(cp) = nv;
    }
  }
}

// ---------------------------------------------------------------------------
// Sparse masked attention. One block (128 threads = 4 head-groups of 32) per
// query s=(t,d1). Keys: t' in {t-1,t} (valid), d2 in adjacency list of d1.
// qkv layout: [S][384] = q|k|v. Output: out[s][h*32+dd].
// ---------------------------------------------------------------------------
__global__ __launch_bounds__(128) void attn_kernel(
    const float* __restrict__ qkv, const float* __restrict__ edge_w,
    float* __restrict__ out) {
  int s = blockIdx.x;
  int t = s / D_, d1 = s - t * D_;
  int tid = threadIdx.x;
  int lane = tid & 63;
  int wv = tid >> 6;
  __shared__ int klist[D_];
  __shared__ int nshare;
  __shared__ float scores[HEADS_][2 * D_];

  if (wv == 0) {  // deterministic ballot-compaction of adjacency row d1
    int cnt = 0;
    for (int base = 0; base < D_; base += 64) {
      int d2 = base + lane;
      bool pred = (edge_w[d1 * D_ + d2] > 0.f) || (d2 == d1);
      unsigned long long mb = __ballot(pred);
      int ofs = __popcll(mb & ((1ull << lane) - 1ull));
      if (pred) klist[cnt + ofs] = d2;
      cnt += __popcll(mb);
    }
    if (lane == 0) nshare = cnt;
  }
  __syncthreads();
  int nd2 = nshare;
  int t0 = (t > 0) ? t - 1 : 0;
  int ntp = (t > 0) ? 2 : 1;
  int nk = nd2 * ntp;

  float q = qkv[s * 384 + tid];
  int h = tid >> 5, dd = tid & 31;

  // scores: wave-cooperative dot per key (4 heads at once)
  for (int tp = 0; tp < ntp; ++tp) {
    int tt = t0 + tp;
    for (int kd = 0; kd < nd2; ++kd) {
      int sk = tt * D_ + klist[kd];
      float partial = q * qkv[sk * 384 + P_ + tid];
      partial += __shfl_xor(partial, 1);
      partial += __shfl_xor(partial, 2);
      partial += __shfl_xor(partial, 4);
      partial += __shfl_xor(partial, 8);
      partial += __shfl_xor(partial, 16);
      if (dd == 0) scores[h][tp * nd2 + kd] = partial * SCALE_;
    }
  }
  __syncthreads();

  // softmax per head over nk scores (32-lane group)
  float mx = -1e30f;
  for (int ki = dd; ki < nk; ki += 32) mx = fmaxf(mx, scores[h][ki]);
  mx = fmaxf(mx, __shfl_xor(mx, 1));
  mx = fmaxf(mx, __shfl_xor(mx, 2));
  mx = fmaxf(mx, __shfl_xor(mx, 4));
  mx = fmaxf(mx, __shfl_xor(mx, 8));
  mx = fmaxf(mx, __shfl_xor(mx, 16));
  float ssum = 0.f;
  for (int ki = dd; ki < nk; ki += 32) {
    float e = expf(scores[h][ki] - mx);
    scores[h][ki] = e;
    ssum += e;
  }
  ssum += __shfl_xor(ssum, 1);
  ssum += __shfl_xor(ssum, 2);
  ssum += __shfl_xor(ssum, 4);
  ssum += __shfl_xor(ssum, 8);
  ssum += __shfl_xor(ssum, 16);
  float inv = 1.f / ssum;
  __syncthreads();

  // PV: out[p] = inv * sum_ki e[ki] * v[key_ki][p]
  float acc = 0.f;
  for (int tp = 0; tp < ntp; ++tp) {
    int tt = t0 + tp;
    for (int kd = 0; kd < nd2; ++kd) {
      float aev = scores[h][tp * nd2 + kd];
      int sk = tt * D_ + klist[kd];
      acc = fmaf(aev, qkv[sk * 384 + 2 * P_ + tid], acc);
    }
  }
  out[s * P_ + tid] = acc * inv;
}

// ---------------------------------------------------------------------------
// Active-logits kernel: one wave per i (nxt node row). Only computes entries
// where edge_w[i][j]!=0 or i==j; rest already filled with -1e9.
// ---------------------------------------------------------------------------
__global__ __launch_bounds__(64) void logits_kernel(
    const float* __restrict__ hn, const float* __restrict__ hc,
    const float* __restrict__ edge_w, const float* __restrict__ W_edge,
    const float* __restrict__ b_edge, const float* __restrict__ Wc1e,
    const float* __restrict__ bc1, const float* __restrict__ Wc2,
    const float* __restrict__ bc2, float* __restrict__ logits) {
  int i = blockIdx.x;
  int lane = threadIdx.x;
  __shared__ int jlist[D_];
  int cnt = 0;
  for (int base = 0; base < D_; base += 64) {
    int j = base + lane;
    bool pred = (edge_w[i * D_ + j] != 0.f) || (j == i);
    unsigned long long mb = __ballot(pred);
    int ofs = __popcll(mb & ((1ull << lane) - 1ull));
    if (pred) jlist[cnt + ofs] = j;
    cnt += __popcll(mb);
  }
  __syncthreads();
  float bc1_0 = bc1[lane], bc1_1 = bc1[lane + 64];
  float wc0 = Wc2[lane], wc1 = Wc2[lane + 64];
  float bb = bc2[0];
  for (int jj = 0; jj < cnt; ++jj) {
    int j = jlist[jj];
    float w = edge_w[i * D_ + j];
    float he0 = 0.f, he1 = 0.f;
    for (int e = 0; e < EC_; ++e) {
      float enc = fmaxf(fmaf(w, W_edge[e], b_edge[e]), 0.f);
      he0 = fmaf(enc, Wc1e[e * P_ + lane], he0);
      he1 = fmaf(enc, Wc1e[e * P_ + lane + 64], he1);
    }
    float base0 = he0 + bc1_0, base1 = he1 + bc1_1;
    for (int t = 0; t < T_ - 1; ++t) {
      const float* hnr = hn + (t * D_ + i) * P_;
      const float* hcr = hc + (t * D_ + j) * P_;
      float sacc = fmaxf(hnr[lane] + hcr[lane] + base0, 0.f) * wc0 +
                   fmaxf(hnr[lane + 64] + hcr[lane + 64] + base1, 0.f) * wc1;
#pragma unroll
      for (int m = 1; m < 64; m <<= 1) sacc += __shfl_xor(sacc, m);
      if (lane == 0) logits[(t * D_ + i) * D_ + j] = sacc + bb;
    }
  }
}

// ---------------------------------------------------------------------------
// Dist head: dist[t,i] = relu(curr@Wd1[:P] + nxt@Wd1[P:] + bd1) @ Wd2 + bd2
// Block = 128 threads handles 4 rows.
// ---------------------------------------------------------------------------
__global__ __launch_bounds__(128) void dist_kernel(
    const float* __restrict__ z, const float* __restrict__ Wd1,
    const float* __restrict__ bd1, const float* __restrict__ Wd2,
    const float* __restrict__ bd2, float* __restrict__ dist) {
  int r0 = blockIdx.x * 4;
  int p = threadIdx.x;
  __shared__ float a[4][2 * P_];
  for (int idx = p; idx < 4 * 2 * P_; idx += 128) {
    int rr = idx >> 8;
    int q = idx & 255;
    a[rr][q] = (q < P_) ? z[(r0 + rr) * P_ + q] : z[(r0 + rr + D_) * P_ + (q - P_)];
  }
  __syncthreads();
  float acc[4];
  float bb = bd1[p];
#pragma unroll
  for (int rr = 0; rr < 4; ++rr) acc[rr] = bb;
  for (int q = 0; q < 2 * P_; ++q) {
    float w = Wd1[q * P_ + p];
#pragma unroll
    for (int rr = 0; rr < 4; ++rr) acc[rr] = fmaf(a[rr][q], w, acc[rr]);
  }
  float wd = Wd2[p];
  __shared__ float red[4][2];
  int lane = p & 63, wv = p >> 6;
#pragma unroll
  for (int rr = 0; rr < 4; ++rr) {
    float s = fmaxf(acc[rr], 0.f) * wd;
#pragma unroll
    for (int m = 1; m < 64; m <<= 1) s += __shfl_xor(s, m);
    if (lane == 0) red[rr][wv] = s;
  }
  __syncthreads();
  if (p < 4) dist[r0 + p] = red[p][0] + red[p][1] + bd2[0];
}

// ---------------------------------------------------------------------------
extern "C" void kernel_launch(void* const* d_in, const int* in_sizes, int n_in,
                              void* d_out, int out_size, void* d_ws,
                              size_t ws_size, hipStream_t stream) {
  const float* x = (const float*)d_in[0];
  const float* edge_w = (const float*)d_in[1];
  const float* W_node = (const float*)d_in[2];
  const float* b_node = (const float*)d_in[3];
  const float* W_edge = (const float*)d_in[4];
  const float* b_edge = (const float*)d_in[5];
  const float* time_enc = (const float*)d_in[6];
  const float* Wqkv = (const float*)d_in[7];
  const float* bqkv = (const float*)d_in[8];
  const float* Wo = (const float*)d_in[9];
  const float* bo = (const float*)d_in[10];
  const float* W1 = (const float*)d_in[11];
  const float* b1 = (const float*)d_in[12];
  const float* W2 = (const float*)d_in[13];
  const float* b2 = (const float*)d_in[14];
  const float* g1 = (const float*)d_in[15];
  const float* beta1 = (const float*)d_in[16];
  const float* g2 = (const float*)d_in[17];
  const float* beta2 = (const float*)d_in[18];
  const float* Wc1 = (const float*)d_in[19];
  const float* bc1 = (const float*)d_in[20];
  const float* Wc2 = (const float*)d_in[21];
  const float* bc2 = (const float*)d_in[22];
  const float* Wd1 = (const float*)d_in[23];
  const float* bd1 = (const float*)d_in[24];
  const float* Wd2 = (const float*)d_in[25];
  const float* bd2 = (const float*)d_in[26];

  float* ws = (float*)d_ws;
  float* y = ws;                        // S*P
  float* qkvb = y + S_ * P_;            // S*3P
  float* attnout = qkvb + S_ * 3 * P_;  // S*P
  float* mid = attnout + S_ * P_;       // S*FF
  float* z = mid + S_ * FF_;            // S*P
  float* hn = qkvb;                     // reuse (15*192*128 <= S*3P)
  float* hc = mid;                      // reuse (15*192*128 <= S*FF)

  float* logits = (float*)d_out;
  float* dist = (float*)d_out + (T_ - 1) * D_ * D_;

  fill_kernel<<<512, 256, 0, stream>>>(logits, -1e9f, (T_ - 1) * D_ * D_);
  node_embed_kernel<<<S_ / 8, 128, 0, stream>>>(x, W_node, b_node, time_enc, z);

  for (int it = 0; it < 2; ++it) {
    ln_kernel<<<S_ / 4, 256, 0, stream>>>(z, g1, beta1, y);
    gemm_k<128, 384, false, false, true><<<S_ / 8, 192, 0, stream>>>(y, Wqkv, bqkv, qkvb);
    attn_kernel<<<S_, 128, 0, stream>>>(qkvb, edge_w, attnout);
    gemm_k<128, 128, false, true, true><<<S_ / 8, 64, 0, stream>>>(attnout, Wo, bo, z);
    ln_kernel<<<S_ / 4, 256, 0, stream>>>(z, g2, beta2, y);
    gemm_k<128, 512, true, false, true><<<S_ / 8, 256, 0, stream>>>(y, W1, b1, mid);
    gemm_k<512, 128, false, true, true><<<S_ / 8, 64, 0, stream>>>(mid, W2, b2, z);
  }

  // hn = nxt @ Wc1[:P], hc = curr @ Wc1[P:2P]   (no bias; bc1 added in logits)
  gemm_k<128, 128, false, false, false><<<(T_ - 1) * D_ / 8, 64, 0, stream>>>(z + D_ * P_, Wc1, nullptr, hn);
  gemm_k<128, 128, false, false, false><<<(T_ - 1) * D_ / 8, 64, 0, stream>>>(z, Wc1 + P_ * P_, nullptr, hc);

  logits_kernel<<<D_, 64, 0, stream>>>(hn, hc, edge_w, W_edge, b_edge,
                                       Wc1 + 2 * P_ * P_, bc1, Wc2, bc2, logits);
  dist_kernel<<<(T_ - 1) * D_ / 4, 128, 0, stream>>>(z, Wd1, bd1, Wd2, bd2, dist);
}

// Round 4
// 356.149 us; speedup vs baseline: 1.4850x; 1.4850x over previous
//
#include <hip/hip_runtime.h>
#include <hip/hip_bf16.h>

// Problem constants
constexpr int T_ = 16;
constexpr int D_ = 192;
constexpr int H_ = 128;
constexpr int P_ = 128;
constexpr int HEADS_ = 4;
constexpr int HD_ = 32;
constexpr int EC_ = 32;
constexpr int S_ = T_ * D_;       // 3072
constexpr int FF_ = 512;
constexpr float SCALE_ = 0.17677669529663687f;  // 1/sqrt(32)

// ---------------------------------------------------------------------------
// Adjacency precompute: one wave per row d1. adj = (edge_w>0) | eye.
// Deterministic ballot compaction.
// ---------------------------------------------------------------------------
__global__ __launch_bounds__(64) void adj_kernel(const float* __restrict__ edge_w,
                                                 int* __restrict__ adj_cnt,
                                                 int* __restrict__ adj_list) {
  int i = blockIdx.x;
  int lane = threadIdx.x;
  int cnt = 0;
  for (int base = 0; base < D_; base += 64) {
    int j = base + lane;
    bool pred = (edge_w[i * D_ + j] > 0.f) || (j == i);
    unsigned long long mb = __ballot(pred);
    int ofs = __popcll(mb & ((1ull << lane) - 1ull));
    if (pred) adj_list[i * D_ + cnt + ofs] = j;
    cnt += __popcll(mb);
  }
  if (lane == 0) adj_cnt[i] = cnt;
}

// ---------------------------------------------------------------------------
// Node embedding: z[s][p] = relu(sum_h x[t][h][d]*W_node[h][p] + b_node[p])
//                           + time_enc[p]*t      (s = t*D + d)
// ---------------------------------------------------------------------------
__global__ __launch_bounds__(128) void node_embed_kernel(
    const float* __restrict__ x, const float* __restrict__ W_node,
    const float* __restrict__ b_node, const float* __restrict__ time_enc,
    float* __restrict__ z) {
  int s0 = blockIdx.x * 8;
  int j = threadIdx.x;  // output column 0..127
  __shared__ float As[8 * H_];
  for (int idx = j; idx < 8 * H_; idx += 128) {
    int r = idx >> 7;
    int h = idx & 127;
    int s = s0 + r;
    int t = s / D_;
    int d = s - t * D_;
    As[idx] = x[(t * H_ + h) * D_ + d];
  }
  __syncthreads();
  float acc[8];
  float bj = b_node[j];
#pragma unroll
  for (int r = 0; r < 8; ++r) acc[r] = bj;
  for (int h = 0; h < H_; h += 4) {
    float4 w;
    w.x = W_node[(h + 0) * P_ + j];
    w.y = W_node[(h + 1) * P_ + j];
    w.z = W_node[(h + 2) * P_ + j];
    w.w = W_node[(h + 3) * P_ + j];
#pragma unroll
    for (int r = 0; r < 8; ++r) {
      const float4 a = *reinterpret_cast<const float4*>(&As[r * H_ + h]);
      acc[r] = fmaf(a.x, w.x, acc[r]);
      acc[r] = fmaf(a.y, w.y, acc[r]);
      acc[r] = fmaf(a.z, w.z, acc[r]);
      acc[r] = fmaf(a.w, w.w, acc[r]);
    }
  }
  float te = time_enc[j];
#pragma unroll
  for (int r = 0; r < 8; ++r) {
    int s = s0 + r;
    int t = s / D_;
    z[s * P_ + j] = fmaxf(acc[r], 0.f) + te * (float)t;
  }
}

// ---------------------------------------------------------------------------
// GEMM: C[M,N] = act(LN?(A)[M,K] @ B[K,N] (+bias)) (+= if ACCUM)
// BM rows per block, CPT=N/NT cols per thread. Optional fused LayerNorm on
// the staged A tile (requires K==128).
// ---------------------------------------------------------------------------
template <int K, int N, int NT, int BM, bool RELU, bool ACCUM, bool BIAS, bool LN>
__global__ __launch_bounds__(NT) void gemm2_k(
    const float* __restrict__ A, const float* __restrict__ B,
    const float* __restrict__ bias, const float* __restrict__ lng,
    const float* __restrict__ lnb, float* __restrict__ C) {
  constexpr int CPT = N / NT;
  int m0 = blockIdx.x * BM;
  int tid = threadIdx.x;
  __shared__ float As[BM * K];
  {
    float4* As4 = reinterpret_cast<float4*>(As);
    const float4* A4 = reinterpret_cast<const float4*>(A + (size_t)m0 * K);
    for (int idx = tid; idx < BM * K / 4; idx += NT) As4[idx] = A4[idx];
  }
  __syncthreads();
  if (LN) {
    static_assert(!LN || K == 128, "LN requires K==128");
    int wv = tid >> 6, lane = tid & 63;
    constexpr int NW = NT / 64;
    for (int r = wv; r < BM; r += NW) {
      float v0 = As[r * K + lane], v1 = As[r * K + 64 + lane];
      float s = v0 + v1;
#pragma unroll
      for (int m = 1; m < 64; m <<= 1) s += __shfl_xor(s, m);
      float mean = s * (1.f / 128.f);
      float d0 = v0 - mean, d1 = v1 - mean;
      float q = d0 * d0 + d1 * d1;
#pragma unroll
      for (int m = 1; m < 64; m <<= 1) q += __shfl_xor(q, m);
      float inv = 1.f / sqrtf(q * (1.f / 128.f) + 1e-5f);
      As[r * K + lane] = d0 * inv * lng[lane] + lnb[lane];
      As[r * K + 64 + lane] = d1 * inv * lng[lane + 64] + lnb[lane + 64];
    }
    __syncthreads();
  }

  if (CPT == 2) {
    int c0 = 2 * tid;
    float acc0[BM], acc1[BM];
    float b0 = BIAS ? bias[c0] : 0.f;
    float b1 = BIAS ? bias[c0 + 1] : 0.f;
#pragma unroll
    for (int r = 0; r < BM; ++r) {
      acc0[r] = b0;
      acc1[r] = b1;
    }
    for (int k = 0; k < K; k += 4) {
      float2 bv0 = *reinterpret_cast<const float2*>(B + (size_t)(k + 0) * N + c0);
      float2 bv1 = *reinterpret_cast<const float2*>(B + (size_t)(k + 1) * N + c0);
      float2 bv2 = *reinterpret_cast<const float2*>(B + (size_t)(k + 2) * N + c0);
      float2 bv3 = *reinterpret_cast<const float2*>(B + (size_t)(k + 3) * N + c0);
#pragma unroll
      for (int r = 0; r < BM; ++r) {
        const float4 a = *reinterpret_cast<const float4*>(&As[r * K + k]);
        acc0[r] = fmaf(a.x, bv0.x, acc0[r]);
        acc1[r] = fmaf(a.x, bv0.y, acc1[r]);
        acc0[r] = fmaf(a.y, bv1.x, acc0[r]);
        acc1[r] = fmaf(a.y, bv1.y, acc1[r]);
        acc0[r] = fmaf(a.z, bv2.x, acc0[r]);
        acc1[r] = fmaf(a.z, bv2.y, acc1[r]);
        acc0[r] = fmaf(a.w, bv3.x, acc0[r]);
        acc1[r] = fmaf(a.w, bv3.y, acc1[r]);
      }
    }
#pragma unroll
    for (int r = 0; r < BM; ++r) {
      float v0 = acc0[r], v1 = acc1[r];
      if (RELU) {
        v0 = fmaxf(v0, 0.f);
        v1 = fmaxf(v1, 0.f);
      }
      float* cp = C + (size_t)(m0 + r) * N + c0;
      if (ACCUM) {
        float2 old = *reinterpret_cast<float2*>(cp);
        old.x += v0;
        old.y += v1;
        *reinterpret_cast<float2*>(cp) = old;
      } else {
        float2 nv;
        nv.x = v0;
        nv.y = v1;
        *reinterpret_cast<float2*>(cp) = nv;
      }
    }
  } else {
    int j = tid;
    float acc[BM];
    float bj = BIAS ? bias[j] : 0.f;
#pragma unroll
    for (int r = 0; r < BM; ++r) acc[r] = bj;
    for (int k = 0; k < K; k += 4) {
      float b0 = B[(size_t)(k + 0) * N + j];
      float b1 = B[(size_t)(k + 1) * N + j];
      float b2 = B[(size_t)(k + 2) * N + j];
      float b3 = B[(size_t)(k + 3) * N + j];
#pragma unroll
      for (int r = 0; r < BM; ++r) {
        const float4 a = *reinterpret_cast<const float4*>(&As[r * K + k]);
        acc[r] = fmaf(a.x, b0, acc[r]);
        acc[r] = fmaf(a.y, b1, acc[r]);
        acc[r] = fmaf(a.z, b2, acc[r]);
        acc[r] = fmaf(a.w, b3, acc[r]);
      }
    }
#pragma unroll
    for (int r = 0; r < BM; ++r) {
      float v = acc[r];
      if (RELU) v = fmaxf(v, 0.f);
      float* cp = C + (size_t)(m0 + r) * N + j;
      if (ACCUM)
        *cp += v;
      else
        *cp = v;
    }
  }
}

// ---------------------------------------------------------------------------
// Head pre-projection GEMM: pre[s][0:128]=z[s]@Wc1[0:128]   (hn source)
//                           pre[s][128:256]=z[s]@Wc1[128:256] (hc source)
//                           pre[s][256:384]=z[s]@Wd1[0:128]  (dist curr)
//                           pre[s][384:512]=z[s]@Wd1[128:256] (dist nxt)
// K=128, N=512, NT=256, CPT=2, BM=8. No bias.
// ---------------------------------------------------------------------------
__global__ __launch_bounds__(256) void pre_gemm_kernel(
    const float* __restrict__ A, const float* __restrict__ Wc1,
    const float* __restrict__ Wd1, float* __restrict__ pre) {
  constexpr int K = 128, N = 512, NT = 256, BM = 8;
  int m0 = blockIdx.x * BM;
  int tid = threadIdx.x;
  __shared__ float As[BM * K];
  {
    float4* As4 = reinterpret_cast<float4*>(As);
    const float4* A4 = reinterpret_cast<const float4*>(A + (size_t)m0 * K);
    for (int idx = tid; idx < BM * K / 4; idx += NT) As4[idx] = A4[idx];
  }
  __syncthreads();
  int c0 = 2 * tid;
  int seg = c0 >> 7;
  int cc = c0 & 127;
  const float* Bbase = (seg < 2 ? Wc1 : Wd1) + ((seg & 1) ? 128 * P_ : 0) + cc;
  float acc0[BM], acc1[BM];
#pragma unroll
  for (int r = 0; r < BM; ++r) {
    acc0[r] = 0.f;
    acc1[r] = 0.f;
  }
  for (int k = 0; k < K; k += 4) {
    float2 bv0 = *reinterpret_cast<const float2*>(Bbase + (size_t)(k + 0) * P_);
    float2 bv1 = *reinterpret_cast<const float2*>(Bbase + (size_t)(k + 1) * P_);
    float2 bv2 = *reinterpret_cast<const float2*>(Bbase + (size_t)(k + 2) * P_);
    float2 bv3 = *reinterpret_cast<const float2*>(Bbase + (size_t)(k + 3) * P_);
#pragma unroll
    for (int r = 0; r < BM; ++r) {
      const float4 a = *reinterpret_cast<const float4*>(&As[r * K + k]);
      acc0[r] = fmaf(a.x, bv0.x, acc0[r]);
      acc1[r] = fmaf(a.x, bv0.y, acc1[r]);
      acc0[r] = fmaf(a.y, bv1.x, acc0[r]);
      acc1[r] = fmaf(a.y, bv1.y, acc1[r]);
      acc0[r] = fmaf(a.z, bv2.x, acc0[r]);
      acc1[r] = fmaf(a.z, bv2.y, acc1[r]);
      acc0[r] = fmaf(a.w, bv3.x, acc0[r]);
      acc1[r] = fmaf(a.w, bv3.y, acc1[r]);
    }
  }
#pragma unroll
  for (int r = 0; r < BM; ++r) {
    float2 nv;
    nv.x = acc0[r];
    nv.y = acc1[r];
    *reinterpret_cast<float2*>(pre + (size_t)(m0 + r) * N + c0) = nv;
  }
}

// ---------------------------------------------------------------------------
// Sparse masked attention. One block (128 threads = 4 head-groups of 32) per
// query s=(t,d1). Keys: t' in {t-1,t} (valid), d2 in adjacency list of d1.
// qkv layout: [S][384] = q|k|v. Output: out[s][h*32+dd].
// ---------------------------------------------------------------------------
__global__ __launch_bounds__(128) void attn_kernel(
    const float* __restrict__ qkv, const int* __restrict__ adj_cnt,
    const int* __restrict__ adj_list, float* __restrict__ out) {
  int s = blockIdx.x;
  int t = s / D_, d1 = s - t * D_;
  int tid = threadIdx.x;
  __shared__ int klist[D_];
  __shared__ float scores[HEADS_][2 * D_];

  int nd2 = adj_cnt[d1];
  for (int kd = tid; kd < nd2; kd += 128) klist[kd] = adj_list[d1 * D_ + kd];
  __syncthreads();
  int t0 = (t > 0) ? t - 1 : 0;
  int ntp = (t > 0) ? 2 : 1;
  int nk = nd2 * ntp;

  float q = qkv[s * 384 + tid];
  int h = tid >> 5, dd = tid & 31;

  // scores: 32-lane cooperative dot per key (4 heads at once)
  for (int tp = 0; tp < ntp; ++tp) {
    int tt = t0 + tp;
    for (int kd = 0; kd < nd2; ++kd) {
      int sk = tt * D_ + klist[kd];
      float partial = q * qkv[sk * 384 + P_ + tid];
      partial += __shfl_xor(partial, 1);
      partial += __shfl_xor(partial, 2);
      partial += __shfl_xor(partial, 4);
      partial += __shfl_xor(partial, 8);
      partial += __shfl_xor(partial, 16);
      if (dd == 0) scores[h][tp * nd2 + kd] = partial * SCALE_;
    }
  }
  __syncthreads();

  // softmax per head over nk scores (32-lane group)
  float mx = -1e30f;
  for (int ki = dd; ki < nk; ki += 32) mx = fmaxf(mx, scores[h][ki]);
  mx = fmaxf(mx, __shfl_xor(mx, 1));
  mx = fmaxf(mx, __shfl_xor(mx, 2));
  mx = fmaxf(mx, __shfl_xor(mx, 4));
  mx = fmaxf(mx, __shfl_xor(mx, 8));
  mx = fmaxf(mx, __shfl_xor(mx, 16));
  float ssum = 0.f;
  for (int ki = dd; ki < nk; ki += 32) {
    float e = expf(scores[h][ki] - mx);
    scores[h][ki] = e;
    ssum += e;
  }
  ssum += __shfl_xor(ssum, 1);
  ssum += __shfl_xor(ssum, 2);
  ssum += __shfl_xor(ssum, 4);
  ssum += __shfl_xor(ssum, 8);
  ssum += __shfl_xor(ssum, 16);
  float inv = 1.f / ssum;
  __syncthreads();

  // PV: out[p] = inv * sum_ki e[ki] * v[key_ki][p]
  float acc = 0.f;
  for (int tp = 0; tp < ntp; ++tp) {
    int tt = t0 + tp;
    for (int kd = 0; kd < nd2; ++kd) {
      float aev = scores[h][tp * nd2 + kd];
      int sk = tt * D_ + klist[kd];
      acc = fmaf(aev, qkv[sk * 384 + 2 * P_ + tid], acc);
    }
  }
  out[s * P_ + tid] = acc * inv;
}

// ---------------------------------------------------------------------------
// Active-logits kernel: grid (D_, T_-1), one wave per (i, t). Writes the full
// -1e9 row, then overwrites active entries (edge_w[i][j]!=0 or i==j).
// hn[t,i] = pre[((t+1)*D+i)*512 + 0:128], hc[t,j] = pre[(t*D+j)*512 + 128:256]
// ---------------------------------------------------------------------------
__global__ __launch_bounds__(64) void logits_kernel(
    const float* __restrict__ pre, const int* __restrict__ adj_cnt,
    const int* __restrict__ adj_list, const float* __restrict__ edge_w,
    const float* __restrict__ W_edge, const float* __restrict__ b_edge,
    const float* __restrict__ Wc1e, const float* __restrict__ bc1,
    const float* __restrict__ Wc2, const float* __restrict__ bc2,
    float* __restrict__ logits) {
  int i = blockIdx.x;
  int t = blockIdx.y;
  int lane = threadIdx.x;
  float* lrow = logits + (size_t)(t * D_ + i) * D_;
  for (int j = lane; j < D_; j += 64) lrow[j] = -1e9f;

  const float* hnr = pre + (size_t)((t + 1) * D_ + i) * 512;
  float hn0 = hnr[lane], hn1 = hnr[lane + 64];
  float bc1_0 = bc1[lane], bc1_1 = bc1[lane + 64];
  float wc0 = Wc2[lane], wc1 = Wc2[lane + 64];
  float bb = bc2[0];
  int cnt = adj_cnt[i];
  for (int jj = 0; jj < cnt; ++jj) {
    int j = adj_list[i * D_ + jj];
    float w = edge_w[i * D_ + j];
    float he0 = 0.f, he1 = 0.f;
#pragma unroll 8
    for (int e = 0; e < EC_; ++e) {
      float enc = fmaxf(fmaf(w, W_edge[e], b_edge[e]), 0.f);
      he0 = fmaf(enc, Wc1e[e * P_ + lane], he0);
      he1 = fmaf(enc, Wc1e[e * P_ + lane + 64], he1);
    }
    const float* hcr = pre + (size_t)(t * D_ + j) * 512 + 128;
    float sacc = fmaxf(hn0 + hcr[lane] + he0 + bc1_0, 0.f) * wc0 +
                 fmaxf(hn1 + hcr[lane + 64] + he1 + bc1_1, 0.f) * wc1;
#pragma unroll
    for (int m = 1; m < 64; m <<= 1) sacc += __shfl_xor(sacc, m);
    if (lane == 0) lrow[j] = sacc + bb;
  }
}

// ---------------------------------------------------------------------------
// Dist epilogue: dist[t,i] = relu(pre[tD+i][256:384] + pre[(t+1)D+i][384:512]
//                                 + bd1) @ Wd2 + bd2.  4 rows per 256-block.
// ---------------------------------------------------------------------------
__global__ __launch_bounds__(256) void dist_kernel(
    const float* __restrict__ pre, const float* __restrict__ bd1,
    const float* __restrict__ Wd2, const float* __restrict__ bd2,
    float* __restrict__ dist) {
  int row = blockIdx.x * 4 + (threadIdx.x >> 6);  // row = t*D + i, t<15
  int lane = threadIdx.x & 63;
  const float* a = pre + (size_t)row * 512 + 256;
  const float* b = pre + (size_t)(row + D_) * 512 + 384;
  float v0 = fmaxf(a[lane] + b[lane] + bd1[lane], 0.f) * Wd2[lane];
  float v1 = fmaxf(a[lane + 64] + b[lane + 64] + bd1[lane + 64], 0.f) * Wd2[lane + 64];
  float s = v0 + v1;
#pragma unroll
  for (int m = 1; m < 64; m <<= 1) s += __shfl_xor(s, m);
  if (lane == 0) dist[row] = s + bd2[0];
}

// ---------------------------------------------------------------------------
extern "C" void kernel_launch(void* const* d_in, const int* in_sizes, int n_in,
                              void* d_out, int out_size, void* d_ws,
                              size_t ws_size, hipStream_t stream) {
  const float* x = (const float*)d_in[0];
  const float* edge_w = (const float*)d_in[1];
  const float* W_node = (const float*)d_in[2];
  const float* b_node = (const float*)d_in[3];
  const float* W_edge = (const float*)d_in[4];
  const float* b_edge = (const float*)d_in[5];
  const float* time_enc = (const float*)d_in[6];
  const float* Wqkv = (const float*)d_in[7];
  const float* bqkv = (const float*)d_in[8];
  const float* Wo = (const float*)d_in[9];
  const float* bo = (const float*)d_in[10];
  const float* W1 = (const float*)d_in[11];
  const float* b1 = (const float*)d_in[12];
  const float* W2 = (const float*)d_in[13];
  const float* b2 = (const float*)d_in[14];
  const float* g1 = (const float*)d_in[15];
  const float* beta1 = (const float*)d_in[16];
  const float* g2 = (const float*)d_in[17];
  const float* beta2 = (const float*)d_in[18];
  const float* Wc1 = (const float*)d_in[19];
  const float* bc1 = (const float*)d_in[20];
  const float* Wc2 = (const float*)d_in[21];
  const float* bc2 = (const float*)d_in[22];
  const float* Wd1 = (const float*)d_in[23];
  const float* bd1 = (const float*)d_in[24];
  const float* Wd2 = (const float*)d_in[25];
  const float* bd2 = (const float*)d_in[26];

  float* ws = (float*)d_ws;
  float* qkvb = ws;                     // S*3P
  float* attnout = qkvb + S_ * 3 * P_;  // S*P
  float* mid = attnout + S_ * P_;       // S*FF (reused as `pre` S*512)
  float* z = mid + S_ * FF_;            // S*P
  int* adj_cnt = (int*)(z + S_ * P_);   // D_
  int* adj_list = adj_cnt + D_;         // D_*D_
  float* pre = mid;

  float* logits = (float*)d_out;
  float* dist = (float*)d_out + (T_ - 1) * D_ * D_;

  adj_kernel<<<D_, 64, 0, stream>>>(edge_w, adj_cnt, adj_list);
  node_embed_kernel<<<S_ / 8, 128, 0, stream>>>(x, W_node, b_node, time_enc, z);

  for (int it = 0; it < 2; ++it) {
    // qkv = LN(z;g1,b1) @ Wqkv + bqkv
    gemm2_k<128, 384, 192, 8, false, false, true, true>
        <<<S_ / 8, 192, 0, stream>>>(z, Wqkv, bqkv, g1, beta1, qkvb);
    attn_kernel<<<S_, 128, 0, stream>>>(qkvb, adj_cnt, adj_list, attnout);
    // z += attnout @ Wo + bo
    gemm2_k<128, 128, 128, 8, false, true, true, false>
        <<<S_ / 8, 128, 0, stream>>>(attnout, Wo, bo, nullptr, nullptr, z);
    // mid = relu(LN(z;g2,b2) @ W1 + b1)
    gemm2_k<128, 512, 256, 8, true, false, true, true>
        <<<S_ / 8, 256, 0, stream>>>(z, W1, b1, g2, beta2, mid);
    // z += mid @ W2 + b2
    gemm2_k<512, 128, 128, 8, false, true, true, false>
        <<<S_ / 8, 128, 0, stream>>>(mid, W2, b2, nullptr, nullptr, z);
  }

  pre_gemm_kernel<<<S_ / 8, 256, 0, stream>>>(z, Wc1, Wd1, pre);

  logits_kernel<<<dim3(D_, T_ - 1), 64, 0, stream>>>(
      pre, adj_cnt, adj_list, edge_w, W_edge, b_edge, Wc1 + 2 * P_ * P_, bc1,
      Wc2, bc2, logits);
  dist_kernel<<<(T_ - 1) * D_ / 4, 256, 0, stream>>>(pre, bd1, Wd2, bd2, dist);
}